// Round 1
// baseline (860.883 us; speedup 1.0000x reference)
//
#include <hip/hip_runtime.h>

#define N 16384
#define IN_F 128
#define OUT_F 32
#define NSPLIT 8   // k-splits in the aggregate kernel

// Kernel A: supT[j][i] = sum_k input[i][k] * weight[k][j]   (transposed support)
// 4 threads per row (k split in quarters), weight staged in LDS, shfl reduce.
__global__ __launch_bounds__(256) void gcn_support(const float* __restrict__ inp,
                                                   const float* __restrict__ w,
                                                   float* __restrict__ supT) {
    __shared__ float wl[IN_F * OUT_F];  // 16 KB
    int tid = threadIdx.x;
#pragma unroll
    for (int u = 0; u < 4; ++u) {
        int idx = (u * 256 + tid) * 4;
        *(float4*)&wl[idx] = *(const float4*)&w[idx];
    }
    __syncthreads();

    int gid = blockIdx.x * 256 + tid;
    int i  = gid >> 2;   // row 0..16383
    int ks = gid & 3;    // k quarter

    float acc[OUT_F];
#pragma unroll
    for (int j = 0; j < OUT_F; ++j) acc[j] = 0.f;

    const float* ip = inp + (size_t)i * IN_F + ks * 32;
#pragma unroll
    for (int kb = 0; kb < 8; ++kb) {
        float4 a4 = *(const float4*)(ip + kb * 4);
        float av[4] = {a4.x, a4.y, a4.z, a4.w};
#pragma unroll
        for (int kk = 0; kk < 4; ++kk) {
            int k = ks * 32 + kb * 4 + kk;
            const float* wr = &wl[k * OUT_F];
#pragma unroll
            for (int j4 = 0; j4 < 8; ++j4) {
                float4 w4 = *(const float4*)(wr + j4 * 4);
                acc[j4 * 4 + 0] = fmaf(av[kk], w4.x, acc[j4 * 4 + 0]);
                acc[j4 * 4 + 1] = fmaf(av[kk], w4.y, acc[j4 * 4 + 1]);
                acc[j4 * 4 + 2] = fmaf(av[kk], w4.z, acc[j4 * 4 + 2]);
                acc[j4 * 4 + 3] = fmaf(av[kk], w4.w, acc[j4 * 4 + 3]);
            }
        }
    }
    // reduce over the 4 k-quarter lanes (xor 1, 2)
#pragma unroll
    for (int j = 0; j < OUT_F; ++j) {
        acc[j] += __shfl_xor(acc[j], 1);
        acc[j] += __shfl_xor(acc[j], 2);
    }
    // each ks lane stores its 8 columns; lanes with same ks have consecutive i -> coalesced
#pragma unroll
    for (int jj = 0; jj < 8; ++jj) {
        int j = ks * 8 + jj;
        supT[(size_t)j * N + i] = acc[j];
    }
}

// Kernel B: out[row][j] += sum_{k in split} adj[row][k] * supT[j][k]
// Wave = 4 row-groups x 16 k-lanes (x float4 -> 64 k per iter).
// Thread: 4 rows x 32 cols in registers. Grid = 256 row-blocks x NSPLIT.
__global__ __launch_bounds__(256, 2) void gcn_aggregate(const float* __restrict__ adj,
                                                        const float* __restrict__ supT,
                                                        float* __restrict__ out) {
    int wg = blockIdx.x;
    int rb = wg >> 3;      // row block 0..255 (64 rows each)
    int sp = wg & 7;       // k split
    int tid  = threadIdx.x;
    int wv   = tid >> 6;
    int lane = tid & 63;
    int rg = lane >> 4;    // row group 0..3
    int kl = lane & 15;    // k lane 0..15

    int rowbase = rb * 64 + wv * 16 + rg * 4;
    int kbase   = sp * (N / NSPLIT) + 4 * kl;

    const float* ap0 = adj + (size_t)(rowbase + 0) * N + kbase;
    const float* ap1 = adj + (size_t)(rowbase + 1) * N + kbase;
    const float* ap2 = adj + (size_t)(rowbase + 2) * N + kbase;
    const float* ap3 = adj + (size_t)(rowbase + 3) * N + kbase;
    const float* bp  = supT + kbase;

    float acc[4][32];
#pragma unroll
    for (int r = 0; r < 4; ++r)
#pragma unroll
        for (int j = 0; j < 32; ++j) acc[r][j] = 0.f;

#pragma unroll 2
    for (int it = 0; it < (N / NSPLIT) / 64; ++it) {
        int off = it * 64;
        float4 a0 = *(const float4*)(ap0 + off);
        float4 a1 = *(const float4*)(ap1 + off);
        float4 a2 = *(const float4*)(ap2 + off);
        float4 a3 = *(const float4*)(ap3 + off);
#pragma unroll
        for (int j = 0; j < 32; ++j) {
            float4 b4 = *(const float4*)(bp + (size_t)j * N + off);
            acc[0][j] = fmaf(a0.x, b4.x, fmaf(a0.y, b4.y, fmaf(a0.z, b4.z, fmaf(a0.w, b4.w, acc[0][j]))));
            acc[1][j] = fmaf(a1.x, b4.x, fmaf(a1.y, b4.y, fmaf(a1.z, b4.z, fmaf(a1.w, b4.w, acc[1][j]))));
            acc[2][j] = fmaf(a2.x, b4.x, fmaf(a2.y, b4.y, fmaf(a2.z, b4.z, fmaf(a2.w, b4.w, acc[2][j]))));
            acc[3][j] = fmaf(a3.x, b4.x, fmaf(a3.y, b4.y, fmaf(a3.z, b4.z, fmaf(a3.w, b4.w, acc[3][j]))));
        }
    }

    // reduce-scatter across the 16 k-lanes; all register indices compile-time,
    // runtime half-selection via cndmask. Final: lane kl holds j = 2*kl, 2*kl+1.
    float r1[4][16];
#pragma unroll
    for (int r = 0; r < 4; ++r)
#pragma unroll
        for (int i = 0; i < 16; ++i) {
            bool hi = (kl & 8) != 0;
            float keep = hi ? acc[r][16 + i] : acc[r][i];
            float send = hi ? acc[r][i] : acc[r][16 + i];
            r1[r][i] = keep + __shfl_xor(send, 8);
        }
    float r2[4][8];
#pragma unroll
    for (int r = 0; r < 4; ++r)
#pragma unroll
        for (int i = 0; i < 8; ++i) {
            bool hi = (kl & 4) != 0;
            float keep = hi ? r1[r][8 + i] : r1[r][i];
            float send = hi ? r1[r][i] : r1[r][8 + i];
            r2[r][i] = keep + __shfl_xor(send, 4);
        }
    float r3[4][4];
#pragma unroll
    for (int r = 0; r < 4; ++r)
#pragma unroll
        for (int i = 0; i < 4; ++i) {
            bool hi = (kl & 2) != 0;
            float keep = hi ? r2[r][4 + i] : r2[r][i];
            float send = hi ? r2[r][i] : r2[r][4 + i];
            r3[r][i] = keep + __shfl_xor(send, 2);
        }
    float r4[4][2];
#pragma unroll
    for (int r = 0; r < 4; ++r)
#pragma unroll
        for (int i = 0; i < 2; ++i) {
            bool hi = (kl & 1) != 0;
            float keep = hi ? r3[r][2 + i] : r3[r][i];
            float send = hi ? r3[r][i] : r3[r][2 + i];
            r4[r][i] = keep + __shfl_xor(send, 1);
        }

#pragma unroll
    for (int r = 0; r < 4; ++r) {
        int row = rowbase + r;
        atomicAdd(&out[row * 32 + 2 * kl + 0], r4[r][0]);
        atomicAdd(&out[row * 32 + 2 * kl + 1], r4[r][1]);
    }
}

__global__ __launch_bounds__(256) void gcn_relu(float* __restrict__ out) {
    int gid = blockIdx.x * 256 + threadIdx.x;  // 131072 float4s
    float4* p = (float4*)out;
    float4 v = p[gid];
    v.x = fmaxf(v.x, 0.f);
    v.y = fmaxf(v.y, 0.f);
    v.z = fmaxf(v.z, 0.f);
    v.w = fmaxf(v.w, 0.f);
    p[gid] = v;
}

extern "C" void kernel_launch(void* const* d_in, const int* in_sizes, int n_in,
                              void* d_out, int out_size, void* d_ws, size_t ws_size,
                              hipStream_t stream) {
    (void)in_sizes; (void)n_in; (void)out_size; (void)ws_size;
    const float* inp = (const float*)d_in[0];   // [16384,128]
    const float* adj = (const float*)d_in[1];   // [16384,16384]
    const float* wgt = (const float*)d_in[2];   // [128,32]
    float* out  = (float*)d_out;                // [16384,32]
    float* supT = (float*)d_ws;                 // [32,16384] = 2 MB scratch

    hipMemsetAsync(out, 0, (size_t)N * OUT_F * sizeof(float), stream);
    gcn_support<<<(N * 4) / 256, 256, 0, stream>>>(inp, wgt, supT);
    gcn_aggregate<<<(N / 64) * NSPLIT, 256, 0, stream>>>(adj, supT, out);
    gcn_relu<<<(N * OUT_F / 4) / 256, 256, 0, stream>>>(out);
}

// Round 2
// 352.591 us; speedup vs baseline: 2.4416x; 2.4416x over previous
//
#include <hip/hip_runtime.h>

#define N 16384
#define IN_F 128
#define OUT_F 32
#define NSPLIT 8            // k-splits in the aggregate kernel
#define KR (N / NSPLIT)     // 2048 k per WG
#define KC 256              // k per LDS chunk (32 KB tile)
#define CHUNKS (KR / KC)    // 8

#define GLOAD_LDS16(g, l) \
    __builtin_amdgcn_global_load_lds((const __attribute__((address_space(1))) void*)(g), \
                                     (__attribute__((address_space(3))) void*)(l), 16, 0, 0)

// Kernel A: supT[j][i] = sum_k input[i][k] * weight[k][j]   (transposed support)
__global__ __launch_bounds__(256) void gcn_support(const float* __restrict__ inp,
                                                   const float* __restrict__ w,
                                                   float* __restrict__ supT) {
    __shared__ float wl[IN_F * OUT_F];  // 16 KB
    int tid = threadIdx.x;
#pragma unroll
    for (int u = 0; u < 4; ++u) {
        int idx = (u * 256 + tid) * 4;
        *(float4*)&wl[idx] = *(const float4*)&w[idx];
    }
    __syncthreads();

    int gid = blockIdx.x * 256 + tid;
    int i  = gid >> 2;   // row 0..16383
    int ks = gid & 3;    // k quarter

    float acc[OUT_F];
#pragma unroll
    for (int j = 0; j < OUT_F; ++j) acc[j] = 0.f;

    const float* ip = inp + (size_t)i * IN_F + ks * 32;
#pragma unroll
    for (int kb = 0; kb < 8; ++kb) {
        float4 a4 = *(const float4*)(ip + kb * 4);
        float av[4] = {a4.x, a4.y, a4.z, a4.w};
#pragma unroll
        for (int kk = 0; kk < 4; ++kk) {
            int k = ks * 32 + kb * 4 + kk;
            const float* wr = &wl[k * OUT_F];
#pragma unroll
            for (int j4 = 0; j4 < 8; ++j4) {
                float4 w4 = *(const float4*)(wr + j4 * 4);
                acc[j4 * 4 + 0] = fmaf(av[kk], w4.x, acc[j4 * 4 + 0]);
                acc[j4 * 4 + 1] = fmaf(av[kk], w4.y, acc[j4 * 4 + 1]);
                acc[j4 * 4 + 2] = fmaf(av[kk], w4.z, acc[j4 * 4 + 2]);
                acc[j4 * 4 + 3] = fmaf(av[kk], w4.w, acc[j4 * 4 + 3]);
            }
        }
    }
#pragma unroll
    for (int j = 0; j < OUT_F; ++j) {
        acc[j] += __shfl_xor(acc[j], 1);
        acc[j] += __shfl_xor(acc[j], 2);
    }
#pragma unroll
    for (int jj = 0; jj < 8; ++jj) {
        int j = ks * 8 + jj;
        supT[(size_t)j * N + i] = acc[j];
    }
}

// Kernel B: out[row][j] += sum_{k in split} adj[row][k] * supT[j][k]
// Wave = jh(2) x rg(4) x kl(8). Thread: 4 rows x 16 cols (64 acc regs).
// supT staged per-chunk into LDS via global_load_lds; adj is the HBM stream.
__global__ __launch_bounds__(256, 3) void gcn_aggregate(const float* __restrict__ adj,
                                                        const float* __restrict__ supT,
                                                        float* __restrict__ out) {
    __shared__ float st[OUT_F * KC];  // 32 KB, layout [j][KC]

    int wg = blockIdx.x;
    int rb = wg >> 3;          // row block 0..255 (64 rows each)
    int sp = wg & 7;           // k split
    int tid  = threadIdx.x;
    int wv   = tid >> 6;
    int lane = tid & 63;
    int jh = lane >> 5;        // j half (bit 5)
    int rg = (lane >> 3) & 3;  // row group (bits 3-4)
    int kl = lane & 7;         // k lane (bits 0-2)

    int rowbase = rb * 64 + wv * 16 + rg * 4;
    int kbase   = sp * KR;

    const float* ap0 = adj + (size_t)(rowbase + 0) * N + kbase + kl * 4;
    const float* ap1 = adj + (size_t)(rowbase + 1) * N + kbase + kl * 4;
    const float* ap2 = adj + (size_t)(rowbase + 2) * N + kbase + kl * 4;
    const float* ap3 = adj + (size_t)(rowbase + 3) * N + kbase + kl * 4;

    float acc[4][16];
#pragma unroll
    for (int r = 0; r < 4; ++r)
#pragma unroll
        for (int j = 0; j < 16; ++j) acc[r][j] = 0.f;

    for (int c = 0; c < CHUNKS; ++c) {
        __syncthreads();  // previous chunk's LDS reads done before overwrite
        // stage supT[0:32][c*KC : (c+1)*KC] -> LDS (8 x dwordx4 per thread, direct to LDS)
#pragma unroll
        for (int u = 0; u < 8; ++u) {
            int f  = u * 256 + tid;        // float4 index in tile, 0..2047
            int j  = f >> 6;               // 64 float4 per j-row
            int k4 = f & 63;
            const float* gp = supT + (size_t)j * N + kbase + c * KC + k4 * 4;
            float* lp = st + (size_t)(u * 1024 + wv * 256);  // wave-uniform base; HW adds lane*16B
            GLOAD_LDS16(gp, lp);
        }
        __syncthreads();  // compiler drains vmcnt before barrier

#pragma unroll 2
        for (int it = 0; it < KC / 32; ++it) {
            int koff = c * KC + it * 32;
            float4 a0 = *(const float4*)(ap0 + koff);
            float4 a1 = *(const float4*)(ap1 + koff);
            float4 a2 = *(const float4*)(ap2 + koff);
            float4 a3 = *(const float4*)(ap3 + koff);
            const float* bbase = st + (size_t)jh * 16 * KC + it * 32 + kl * 4;
#pragma unroll
            for (int jj = 0; jj < 16; ++jj) {
                float4 b4 = *(const float4*)(bbase + (size_t)jj * KC);
                acc[0][jj] = fmaf(a0.x, b4.x, fmaf(a0.y, b4.y, fmaf(a0.z, b4.z, fmaf(a0.w, b4.w, acc[0][jj]))));
                acc[1][jj] = fmaf(a1.x, b4.x, fmaf(a1.y, b4.y, fmaf(a1.z, b4.z, fmaf(a1.w, b4.w, acc[1][jj]))));
                acc[2][jj] = fmaf(a2.x, b4.x, fmaf(a2.y, b4.y, fmaf(a2.z, b4.z, fmaf(a2.w, b4.w, acc[2][jj]))));
                acc[3][jj] = fmaf(a3.x, b4.x, fmaf(a3.y, b4.y, fmaf(a3.z, b4.z, fmaf(a3.w, b4.w, acc[3][jj]))));
            }
        }
    }

    // Reduce-scatter across the 8 k-lanes (masks 4,2,1). All register indices
    // compile-time; runtime half-selection via cndmask.
    float r1[4][8];
#pragma unroll
    for (int r = 0; r < 4; ++r)
#pragma unroll
        for (int i = 0; i < 8; ++i) {
            bool hi = (kl & 4) != 0;
            float keep = hi ? acc[r][8 + i] : acc[r][i];
            float send = hi ? acc[r][i] : acc[r][8 + i];
            r1[r][i] = keep + __shfl_xor(send, 4);
        }
    float r2[4][4];
#pragma unroll
    for (int r = 0; r < 4; ++r)
#pragma unroll
        for (int i = 0; i < 4; ++i) {
            bool hi = (kl & 2) != 0;
            float keep = hi ? r1[r][4 + i] : r1[r][i];
            float send = hi ? r1[r][i] : r1[r][4 + i];
            r2[r][i] = keep + __shfl_xor(send, 2);
        }
    float r3[4][2];
#pragma unroll
    for (int r = 0; r < 4; ++r)
#pragma unroll
        for (int i = 0; i < 2; ++i) {
            bool hi = (kl & 1) != 0;
            float keep = hi ? r2[r][2 + i] : r2[r][i];
            float send = hi ? r2[r][i] : r2[r][2 + i];
            r3[r][i] = keep + __shfl_xor(send, 1);
        }

    // lane (jh,rg,kl) holds cols j = jh*16 + 2*kl + {0,1} for its 4 rows
#pragma unroll
    for (int r = 0; r < 4; ++r) {
        int row = rowbase + r;
        int j   = jh * 16 + 2 * kl;
        atomicAdd(&out[row * 32 + j + 0], r3[r][0]);
        atomicAdd(&out[row * 32 + j + 1], r3[r][1]);
    }
}

__global__ __launch_bounds__(256) void gcn_relu(float* __restrict__ out) {
    int gid = blockIdx.x * 256 + threadIdx.x;  // 131072 float4s
    float4* p = (float4*)out;
    float4 v = p[gid];
    v.x = fmaxf(v.x, 0.f);
    v.y = fmaxf(v.y, 0.f);
    v.z = fmaxf(v.z, 0.f);
    v.w = fmaxf(v.w, 0.f);
    p[gid] = v;
}

extern "C" void kernel_launch(void* const* d_in, const int* in_sizes, int n_in,
                              void* d_out, int out_size, void* d_ws, size_t ws_size,
                              hipStream_t stream) {
    (void)in_sizes; (void)n_in; (void)out_size; (void)ws_size;
    const float* inp = (const float*)d_in[0];   // [16384,128]
    const float* adj = (const float*)d_in[1];   // [16384,16384]
    const float* wgt = (const float*)d_in[2];   // [128,32]
    float* out  = (float*)d_out;                // [16384,32]
    float* supT = (float*)d_ws;                 // [32,16384] = 2 MB scratch

    hipMemsetAsync(out, 0, (size_t)N * OUT_F * sizeof(float), stream);
    gcn_support<<<(N * 4) / 256, 256, 0, stream>>>(inp, wgt, supT);
    gcn_aggregate<<<(N / 64) * NSPLIT, 256, 0, stream>>>(adj, supT, out);
    gcn_relu<<<(N * OUT_F / 4) / 256, 256, 0, stream>>>(out);
}

// Round 3
// 340.012 us; speedup vs baseline: 2.5319x; 1.0370x over previous
//
#include <hip/hip_runtime.h>

#define N 16384
#define IN_F 128
#define OUT_F 32
#define NSPLIT 4            // k-splits in the aggregate kernel
#define KR (N / NSPLIT)     // 4096 k per WG
#define KC 128              // k per LDS chunk (16 KB tile)
#define CHUNKS (KR / KC)    // 32

#define GLOAD_LDS16(g, l) \
    __builtin_amdgcn_global_load_lds((const __attribute__((address_space(1))) void*)(g), \
                                     (__attribute__((address_space(3))) void*)(l), 16, 0, 0)

// Kernel A: supT[j][i] = sum_k input[i][k] * weight[k][j]   (transposed support)
__global__ __launch_bounds__(256) void gcn_support(const float* __restrict__ inp,
                                                   const float* __restrict__ w,
                                                   float* __restrict__ supT) {
    __shared__ float wl[IN_F * OUT_F];  // 16 KB
    int tid = threadIdx.x;
#pragma unroll
    for (int u = 0; u < 4; ++u) {
        int idx = (u * 256 + tid) * 4;
        *(float4*)&wl[idx] = *(const float4*)&w[idx];
    }
    __syncthreads();

    int gid = blockIdx.x * 256 + tid;
    int i  = gid >> 2;   // row 0..16383
    int ks = gid & 3;    // k quarter

    float acc[OUT_F];
#pragma unroll
    for (int j = 0; j < OUT_F; ++j) acc[j] = 0.f;

    const float* ip = inp + (size_t)i * IN_F + ks * 32;
#pragma unroll
    for (int kb = 0; kb < 8; ++kb) {
        float4 a4 = *(const float4*)(ip + kb * 4);
        float av[4] = {a4.x, a4.y, a4.z, a4.w};
#pragma unroll
        for (int kk = 0; kk < 4; ++kk) {
            int k = ks * 32 + kb * 4 + kk;
            const float* wr = &wl[k * OUT_F];
#pragma unroll
            for (int j4 = 0; j4 < 8; ++j4) {
                float4 w4 = *(const float4*)(wr + j4 * 4);
                acc[j4 * 4 + 0] = fmaf(av[kk], w4.x, acc[j4 * 4 + 0]);
                acc[j4 * 4 + 1] = fmaf(av[kk], w4.y, acc[j4 * 4 + 1]);
                acc[j4 * 4 + 2] = fmaf(av[kk], w4.z, acc[j4 * 4 + 2]);
                acc[j4 * 4 + 3] = fmaf(av[kk], w4.w, acc[j4 * 4 + 3]);
            }
        }
    }
#pragma unroll
    for (int j = 0; j < OUT_F; ++j) {
        acc[j] += __shfl_xor(acc[j], 1);
        acc[j] += __shfl_xor(acc[j], 2);
    }
#pragma unroll
    for (int jj = 0; jj < 8; ++jj) {
        int j = ks * 8 + jj;
        supT[(size_t)j * N + i] = acc[j];
    }
}

// Kernel B: out[row][j] += sum_{k in split} adj[row][k] * supT[j][k]
// Wave = jh(2) x rg(4) x kl(8). Thread: 4 rows x 16 cols (64 acc regs).
// supT double-buffered in LDS via global_load_lds (2-phase pipeline:
// issue chunk c+1's staging BEFORE computing chunk c; single barrier/chunk).
__global__ __launch_bounds__(256, 4) void gcn_aggregate(const float* __restrict__ adj,
                                                        const float* __restrict__ supT,
                                                        float* __restrict__ out) {
    __shared__ float st[2 * OUT_F * KC];  // 2 x 16 KB, layout [buf][j][KC]

    int wg = blockIdx.x;
    int rb = wg >> 2;          // row block 0..255 (64 rows each)
    int sp = wg & 3;           // k split
    int tid  = threadIdx.x;
    int wv   = tid >> 6;
    int lane = tid & 63;
    int jh = lane >> 5;        // j half (bit 5)
    int rg = (lane >> 3) & 3;  // row group (bits 3-4)
    int kl = lane & 7;         // k lane (bits 0-2)

    int rowbase = rb * 64 + wv * 16 + rg * 4;
    int kbase   = sp * KR;

    const float* ap0 = adj + (size_t)(rowbase + 0) * N + kbase + kl * 4;
    const float* ap1 = adj + (size_t)(rowbase + 1) * N + kbase + kl * 4;
    const float* ap2 = adj + (size_t)(rowbase + 2) * N + kbase + kl * 4;
    const float* ap3 = adj + (size_t)(rowbase + 3) * N + kbase + kl * 4;

    float acc[4][16];
#pragma unroll
    for (int r = 0; r < 4; ++r)
#pragma unroll
        for (int j = 0; j < 16; ++j) acc[r][j] = 0.f;

    // stage tile for chunk c into buffer buf (4 x dwordx4 per thread, direct to LDS)
    auto stage = [&](int buf, int c) {
#pragma unroll
        for (int u = 0; u < 4; ++u) {
            int f  = u * 256 + tid;        // float4 index in 16KB tile, 0..1023
            int j  = f >> 5;               // 32 float4 per j-row
            int k4 = f & 31;
            const float* gp = supT + (size_t)j * N + kbase + c * KC + k4 * 4;
            float* lp = st + buf * (OUT_F * KC) + u * 1024 + wv * 256;  // wave-uniform base; HW adds lane*16B
            GLOAD_LDS16(gp, lp);
        }
    };

    stage(0, 0);
    __syncthreads();  // drain prologue staging

    for (int c = 0; c < CHUNKS; ++c) {
        int cur = c & 1;
        if (c + 1 < CHUNKS) stage(cur ^ 1, c + 1);  // async: in flight across compute

        const float* sb = st + cur * (OUT_F * KC) + jh * 16 * KC + kl * 4;
#pragma unroll 2
        for (int it = 0; it < KC / 32; ++it) {
            int koff = c * KC + it * 32;
            float4 a0 = *(const float4*)(ap0 + koff);
            float4 a1 = *(const float4*)(ap1 + koff);
            float4 a2 = *(const float4*)(ap2 + koff);
            float4 a3 = *(const float4*)(ap3 + koff);
            const float* bbase = sb + it * 32;
#pragma unroll
            for (int jj = 0; jj < 16; ++jj) {
                float4 b4 = *(const float4*)(bbase + (size_t)jj * KC);
                acc[0][jj] = fmaf(a0.x, b4.x, fmaf(a0.y, b4.y, fmaf(a0.z, b4.z, fmaf(a0.w, b4.w, acc[0][jj]))));
                acc[1][jj] = fmaf(a1.x, b4.x, fmaf(a1.y, b4.y, fmaf(a1.z, b4.z, fmaf(a1.w, b4.w, acc[1][jj]))));
                acc[2][jj] = fmaf(a2.x, b4.x, fmaf(a2.y, b4.y, fmaf(a2.z, b4.z, fmaf(a2.w, b4.w, acc[2][jj]))));
                acc[3][jj] = fmaf(a3.x, b4.x, fmaf(a3.y, b4.y, fmaf(a3.z, b4.z, fmaf(a3.w, b4.w, acc[3][jj]))));
            }
        }
        __syncthreads();  // drains staging vmcnt (hidden by compute) + protects buf reuse
    }

    // Reduce-scatter across the 8 k-lanes (masks 4,2,1). All register indices
    // compile-time; runtime half-selection via cndmask.
    float r1[4][8];
#pragma unroll
    for (int r = 0; r < 4; ++r)
#pragma unroll
        for (int i = 0; i < 8; ++i) {
            bool hi = (kl & 4) != 0;
            float keep = hi ? acc[r][8 + i] : acc[r][i];
            float send = hi ? acc[r][i] : acc[r][8 + i];
            r1[r][i] = keep + __shfl_xor(send, 4);
        }
    float r2[4][4];
#pragma unroll
    for (int r = 0; r < 4; ++r)
#pragma unroll
        for (int i = 0; i < 4; ++i) {
            bool hi = (kl & 2) != 0;
            float keep = hi ? r1[r][4 + i] : r1[r][i];
            float send = hi ? r1[r][i] : r1[r][4 + i];
            r2[r][i] = keep + __shfl_xor(send, 2);
        }
    float r3[4][2];
#pragma unroll
    for (int r = 0; r < 4; ++r)
#pragma unroll
        for (int i = 0; i < 2; ++i) {
            bool hi = (kl & 1) != 0;
            float keep = hi ? r2[r][2 + i] : r2[r][i];
            float send = hi ? r2[r][i] : r2[r][2 + i];
            r3[r][i] = keep + __shfl_xor(send, 1);
        }

    // lane (jh,rg,kl) holds cols j = jh*16 + 2*kl + {0,1} for its 4 rows
#pragma unroll
    for (int r = 0; r < 4; ++r) {
        int row = rowbase + r;
        int j   = jh * 16 + 2 * kl;
        atomicAdd(&out[row * 32 + j + 0], r3[r][0]);
        atomicAdd(&out[row * 32 + j + 1], r3[r][1]);
    }
}

__global__ __launch_bounds__(256) void gcn_relu(float* __restrict__ out) {
    int gid = blockIdx.x * 256 + threadIdx.x;  // 131072 float4s
    float4* p = (float4*)out;
    float4 v = p[gid];
    v.x = fmaxf(v.x, 0.f);
    v.y = fmaxf(v.y, 0.f);
    v.z = fmaxf(v.z, 0.f);
    v.w = fmaxf(v.w, 0.f);
    p[gid] = v;
}

extern "C" void kernel_launch(void* const* d_in, const int* in_sizes, int n_in,
                              void* d_out, int out_size, void* d_ws, size_t ws_size,
                              hipStream_t stream) {
    (void)in_sizes; (void)n_in; (void)out_size; (void)ws_size;
    const float* inp = (const float*)d_in[0];   // [16384,128]
    const float* adj = (const float*)d_in[1];   // [16384,16384]
    const float* wgt = (const float*)d_in[2];   // [128,32]
    float* out  = (float*)d_out;                // [16384,32]
    float* supT = (float*)d_ws;                 // [32,16384] = 2 MB scratch

    hipMemsetAsync(out, 0, (size_t)N * OUT_F * sizeof(float), stream);
    gcn_support<<<(N * 4) / 256, 256, 0, stream>>>(inp, wgt, supT);
    gcn_aggregate<<<(N / 64) * NSPLIT, 256, 0, stream>>>(adj, supT, out);
    gcn_relu<<<(N * OUT_F / 4) / 256, 256, 0, stream>>>(out);
}